// Round 1
// baseline (193.174 us; speedup 1.0000x reference)
//
#include <hip/hip_runtime.h>
#include <stdint.h>

#define CC 22
#define START_I 20
#define STOP_I 21
#define BB 64
#define LL 512
#define DD 512
#define NEGV -100000.0f

// ws layout
#define EMIT_FLOATS ((BB * LL + 8) * CC)                 // + 8 rows prefetch slack
#define BP_OFF (((EMIT_FLOATS * 4) + 255) & ~255)
#define BP_BYTES (BB * LL * CC)
#define META_OFF ((BP_OFF + BP_BYTES + 255) & ~255)

// ---------------- emissions GEMM: emit[row][c] = x[row]·W[c] + b[c] ----------------
__global__ __launch_bounds__(256) void k_emit(const float* __restrict__ x,
                                              const float* __restrict__ W,
                                              const float* __restrict__ bias,
                                              float* __restrict__ emit) {
  __shared__ float Wl[CC * 516];  // row-major, stride 516 (16B aligned, bank-spread)
  int tid = threadIdx.x;
  for (int g = tid; g < CC * DD; g += 256) {
    int c = g >> 9;
    int d = g & (DD - 1);
    Wl[c * 516 + d] = W[g];
  }
  __syncthreads();
  int gtid = blockIdx.x * 256 + tid;  // 704*256 = 180224 = 22 * 8192 exactly
  int c = gtid % CC;
  int rowbase = gtid / CC;            // [0, 8192)
  float bc = bias[c];
  const float4* xr = (const float4*)(x + (size_t)rowbase * DD);
  const int RS = 8192 * (DD / 4);     // float4 stride between the 4 row groups
  const float* wrow = Wl + c * 516;
  float acc0 = 0.f, acc1 = 0.f, acc2 = 0.f, acc3 = 0.f;
#pragma unroll 4
  for (int i = 0; i < DD / 4; ++i) {
    float4 wv = *(const float4*)(wrow + 4 * i);
    float4 a0 = xr[i];
    float4 a1 = xr[i + RS];
    float4 a2 = xr[i + 2 * RS];
    float4 a3 = xr[i + 3 * RS];
    acc0 += a0.x * wv.x + a0.y * wv.y + a0.z * wv.z + a0.w * wv.w;
    acc1 += a1.x * wv.x + a1.y * wv.y + a1.z * wv.z + a1.w * wv.w;
    acc2 += a2.x * wv.x + a2.y * wv.y + a2.z * wv.z + a2.w * wv.w;
    acc3 += a3.x * wv.x + a3.y * wv.y + a3.z * wv.z + a3.w * wv.w;
  }
  emit[(size_t)(rowbase +     0) * CC + c] = acc0 + bc;
  emit[(size_t)(rowbase +  8192) * CC + c] = acc1 + bc;
  emit[(size_t)(rowbase + 16384) * CC + c] = acc2 + bc;
  emit[(size_t)(rowbase + 24576) * CC + c] = acc3 + bc;
}

// ---------------- Viterbi forward scan: one wave per batch ----------------
__device__ __forceinline__ float swz_f(float v) {  // xor-1 lane swap (pair exchange)
  return __int_as_float(__builtin_amdgcn_ds_swizzle(__float_as_int(v), 0x041F));
}
__device__ __forceinline__ unsigned swz_u(unsigned v) {
  return (unsigned)__builtin_amdgcn_ds_swizzle((int)v, 0x041F);
}
__device__ __forceinline__ float bperm_f(int addr, float v) {
  return __int_as_float(__builtin_amdgcn_ds_bpermute(addr, __float_as_int(v)));
}

__global__ __launch_bounds__(64) void k_scan(const float* __restrict__ emit,
                                             const float* __restrict__ mask,
                                             const float* __restrict__ trans,
                                             float* __restrict__ out_score,
                                             unsigned char* __restrict__ bp,
                                             int* __restrict__ meta) {
  const int b = blockIdx.x;
  const int lane = threadIdx.x;
  const int to = lane >> 1;
  const int h = lane & 1;
  const int toc = to < CC ? to : CC - 1;  // clamp for idle lanes 44..63

  float Tf[11];  // T[to][11h + j]
#pragma unroll
  for (int j = 0; j < 11; ++j) Tf[j] = trans[toc * CC + 11 * h + j];
  const float Tstop = trans[STOP_I * CC + toc];

  // seq_len via ballots over the right-padded mask
  int n = 0;
#pragma unroll
  for (int k = 0; k < 8; ++k) {
    unsigned long long bl = __ballot(mask[b * LL + k * 64 + lane] > 0.0f);
    n += __popcll(bl);
  }
  const int n4 = (n + 3) & ~3;
  const int abase = 88 * h;  // bpermute byte addr base: 4 * (2*(11h))

  float ms = (toc == START_I) ? 0.0f : NEGV;  // both pair lanes hold ms[to]
  const float* eb = emit + (size_t)b * LL * CC;
  unsigned char* bpb = bp + (size_t)b * LL * CC;

  float eA0 = eb[0 * CC + toc], eA1 = eb[1 * CC + toc],
        eA2 = eb[2 * CC + toc], eA3 = eb[3 * CC + toc];

  for (int t = 0; t < n4; t += 4) {
    // prefetch next block of emissions (slack rows make tail reads safe)
    float eB0 = eb[(t + 4) * CC + toc];
    float eB1 = eb[(t + 5) * CC + toc];
    float eB2 = eb[(t + 6) * CC + toc];
    float eB3 = eb[(t + 7) * CC + toc];
#pragma unroll
    for (int q = 0; q < 4; ++q) {
      float e = (q == 0) ? eA0 : (q == 1) ? eA1 : (q == 2) ? eA2 : eA3;
      int tt = t + q;
      float cand[11];
#pragma unroll
      for (int j = 0; j < 11; ++j)
        cand[j] = bperm_f(abase + 8 * j, ms) + Tf[j];  // gather ms[frm] from lane 2*frm
      float m01 = fmaxf(cand[0], cand[1]);
      float m23 = fmaxf(cand[2], cand[3]);
      float m45 = fmaxf(cand[4], cand[5]);
      float m67 = fmaxf(cand[6], cand[7]);
      float m89 = fmaxf(cand[8], cand[9]);
      float mxh = fmaxf(fmaxf(fmaxf(m01, m23), fmaxf(m45, m67)), fmaxf(m89, cand[10]));
      float mx = fmaxf(mxh, swz_f(mxh));  // cross-pair max -> global max over 22
      // first-index argmax: equality bitmask + ctz (matches jnp.argmax ties)
      unsigned u = 0;
#pragma unroll
      for (int j = 10; j >= 0; --j) u = (u << 1) | (unsigned)(cand[j] == mx);
      unsigned uo = swz_u(u);
      unsigned lo = h ? uo : u;
      unsigned hi = h ? u : uo;
      unsigned full = lo | (hi << 11) | (1u << 22);
      int bpi = __builtin_ctz(full);
      bool act = tt < n;
      float st = mx + e;
      ms = act ? st : ms;
      if (act && h == 0 && to < CC) bpb[tt * CC + to] = (unsigned char)bpi;
    }
    eA0 = eB0; eA1 = eB1; eA2 = eB2; eA3 = eB3;
  }

  float fin = ms + Tstop;
  if (h == 0 && to < CC) out_score[b * CC + to] = fin;

  // best tag: uniform readlane sweep (strict > keeps first index on ties)
  float bv = -3.0e38f; int bt = 0;
#pragma unroll
  for (int k = 0; k < CC; ++k) {
    float v = __int_as_float(__builtin_amdgcn_readlane(__float_as_int(fin), 2 * k));
    bool g = v > bv;
    bv = g ? v : bv;
    bt = g ? k : bt;
  }
  if (lane == 0) { meta[b] = n; meta[BB + b] = bt; }
}

// ---------------- backtrace: chunk-composed backpointer maps ----------------
__global__ __launch_bounds__(64) void k_back(const unsigned char* __restrict__ bp,
                                             const int* __restrict__ meta,
                                             float* __restrict__ out_path) {
  __shared__ __align__(16) unsigned char bps[LL * CC];  // 11264 B
  __shared__ unsigned char gs[64 * CC];                 // per-chunk composed maps
  const int b = blockIdx.x, lane = threadIdx.x;
  const int n = meta[b];
  const int bt = meta[BB + b];
  const uint32_t* src = (const uint32_t*)(bp + (size_t)b * LL * CC);
  uint32_t* dst = (uint32_t*)bps;
  for (int i = lane; i < (LL * CC) / 4; i += 64) dst[i] = src[i];
  __syncthreads();
  // lane k composes the 8-step map of chunk k (inactive steps = identity)
  const int k = lane;
  for (int c = 0; c < CC; ++c) {
    int tag = c;
#pragma unroll
    for (int j = 7; j >= 0; --j) {
      int t = 8 * k + j;
      int nv = bps[t * CC + tag];
      tag = (t < n) ? nv : tag;
    }
    gs[k * CC + c] = (unsigned char)tag;
  }
  __syncthreads();
  // 64-step dependent chain over chunk maps (broadcast LDS reads)
  int tag = bt, entry = bt;
  for (int kk = 63; kk >= 0; --kk) {
    if (lane == kk) entry = tag;
    tag = gs[kk * CC + tag];
  }
  // parallel replay within each chunk
  tag = entry;
  float* op = out_path + (size_t)b * LL;
#pragma unroll
  for (int j = 7; j >= 0; --j) {
    int t = 8 * k + j;
    bool act = t < n;
    op[t] = act ? (float)tag : 0.0f;
    int nv = bps[t * CC + tag];
    tag = act ? nv : tag;
  }
}

extern "C" void kernel_launch(void* const* d_in, const int* in_sizes, int n_in,
                              void* d_out, int out_size, void* d_ws, size_t ws_size,
                              hipStream_t stream) {
  const float* x = (const float*)d_in[0];
  const float* mask = (const float*)d_in[1];
  const float* W = (const float*)d_in[2];
  const float* bias = (const float*)d_in[3];
  const float* trans = (const float*)d_in[4];
  float* out_score = (float*)d_out;                 // [B, C] f32
  float* out_path = (float*)d_out + BB * CC;        // [B, L] written as f32 values
  char* ws = (char*)d_ws;
  float* emit = (float*)ws;
  unsigned char* bp = (unsigned char*)(ws + BP_OFF);
  int* meta = (int*)(ws + META_OFF);

  k_emit<<<dim3(704), dim3(256), 0, stream>>>(x, W, bias, emit);
  k_scan<<<dim3(BB), dim3(64), 0, stream>>>(emit, mask, trans, out_score, bp, meta);
  k_back<<<dim3(BB), dim3(64), 0, stream>>>(bp, meta, out_path);
}

// Round 2
// 160.765 us; speedup vs baseline: 1.2016x; 1.2016x over previous
//
#include <hip/hip_runtime.h>
#include <stdint.h>

#define CC 22
#define START_I 20
#define STOP_I 21
#define BB 64
#define LL 512
#define DD 512
#define NEGV -100000.0f
#define NCH 32
#define CS 16

// ws layout
#define EMIT_FLOATS ((BB * LL + CS) * CC)                // + CS rows prefetch slack
#define BP_OFF (((EMIT_FLOATS * 4) + 255) & ~255)
#define BP_BYTES (BB * LL * CC)
#define META_OFF ((BP_OFF + BP_BYTES + 255) & ~255)
#define PV_OFF (META_OFF + 1024)                         // 64*32*22 floats = 180224 B

// ---------------- emissions GEMM: emit[row][c] = x[row]·W[c] + b[c] ----------------
__global__ __launch_bounds__(256) void k_emit(const float* __restrict__ x,
                                              const float* __restrict__ W,
                                              const float* __restrict__ bias,
                                              float* __restrict__ emit) {
  __shared__ float Wl[CC * 516];  // row-major, stride 516 (16B aligned, bank-spread)
  int tid = threadIdx.x;
  for (int g = tid; g < CC * DD; g += 256) {
    int c = g >> 9;
    int d = g & (DD - 1);
    Wl[c * 516 + d] = W[g];
  }
  __syncthreads();
  int gtid = blockIdx.x * 256 + tid;  // 704*256 = 180224 = 22 * 8192 exactly
  int c = gtid % CC;
  int rowbase = gtid / CC;            // [0, 8192)
  float bc = bias[c];
  const float4* xr = (const float4*)(x + (size_t)rowbase * DD);
  const int RS = 8192 * (DD / 4);     // float4 stride between the 4 row groups
  const float* wrow = Wl + c * 516;
  float acc0 = 0.f, acc1 = 0.f, acc2 = 0.f, acc3 = 0.f;
#pragma unroll 4
  for (int i = 0; i < DD / 4; ++i) {
    float4 wv = *(const float4*)(wrow + 4 * i);
    float4 a0 = xr[i];
    float4 a1 = xr[i + RS];
    float4 a2 = xr[i + 2 * RS];
    float4 a3 = xr[i + 3 * RS];
    acc0 += a0.x * wv.x + a0.y * wv.y + a0.z * wv.z + a0.w * wv.w;
    acc1 += a1.x * wv.x + a1.y * wv.y + a1.z * wv.z + a1.w * wv.w;
    acc2 += a2.x * wv.x + a2.y * wv.y + a2.z * wv.z + a2.w * wv.w;
    acc3 += a3.x * wv.x + a3.y * wv.y + a3.z * wv.z + a3.w * wv.w;
  }
  emit[(size_t)(rowbase +     0) * CC + c] = acc0 + bc;
  emit[(size_t)(rowbase +  8192) * CC + c] = acc1 + bc;
  emit[(size_t)(rowbase + 16384) * CC + c] = acc2 + bc;
  emit[(size_t)(rowbase + 24576) * CC + c] = acc3 + bc;
}

__device__ __forceinline__ float rlf(float v, int l) {
  return __int_as_float(__builtin_amdgcn_readlane(__float_as_int(v), l));
}

// One Viterbi max-step: st' = max_frm(st[frm] + Trow[frm]) + EV
// Broadcast via v_readlane (no LDS latency); max3-fusable tree.
#define VSTEP(EV)                                                 \
  {                                                               \
    float c0  = rlf(st, 0)  + Trow[0];                            \
    float c1  = rlf(st, 1)  + Trow[1];                            \
    float c2  = rlf(st, 2)  + Trow[2];                            \
    float c3  = rlf(st, 3)  + Trow[3];                            \
    float c4  = rlf(st, 4)  + Trow[4];                            \
    float c5  = rlf(st, 5)  + Trow[5];                            \
    float c6  = rlf(st, 6)  + Trow[6];                            \
    float c7  = rlf(st, 7)  + Trow[7];                            \
    float c8  = rlf(st, 8)  + Trow[8];                            \
    float c9  = rlf(st, 9)  + Trow[9];                            \
    float c10 = rlf(st, 10) + Trow[10];                           \
    float c11 = rlf(st, 11) + Trow[11];                           \
    float c12 = rlf(st, 12) + Trow[12];                           \
    float c13 = rlf(st, 13) + Trow[13];                           \
    float c14 = rlf(st, 14) + Trow[14];                           \
    float c15 = rlf(st, 15) + Trow[15];                           \
    float c16 = rlf(st, 16) + Trow[16];                           \
    float c17 = rlf(st, 17) + Trow[17];                           \
    float c18 = rlf(st, 18) + Trow[18];                           \
    float c19 = rlf(st, 19) + Trow[19];                           \
    float c20 = rlf(st, 20) + Trow[20];                           \
    float c21 = rlf(st, 21) + Trow[21];                           \
    float m0 = fmaxf(fmaxf(c0, c1), c2);                          \
    float m1 = fmaxf(fmaxf(c3, c4), c5);                          \
    float m2 = fmaxf(fmaxf(c6, c7), c8);                          \
    float m3 = fmaxf(fmaxf(c9, c10), c11);                        \
    float m4 = fmaxf(fmaxf(c12, c13), c14);                       \
    float m5 = fmaxf(fmaxf(c15, c16), c17);                       \
    float m6 = fmaxf(fmaxf(c18, c19), c20);                       \
    float n0 = fmaxf(fmaxf(m0, m1), m2);                          \
    float n1 = fmaxf(fmaxf(m3, m4), m5);                          \
    float n2 = fmaxf(m6, c21);                                    \
    float mx = fmaxf(fmaxf(n0, n1), n2);                          \
    st = mx + (EV);                                               \
  }

// ---------------- prefix pass: exact scores only, checkpoint every CS steps ----------
__global__ __launch_bounds__(64) void k_pfx(const float* __restrict__ emit,
                                            const float* __restrict__ mask,
                                            const float* __restrict__ trans,
                                            float* __restrict__ out_score,
                                            float* __restrict__ pv,
                                            int* __restrict__ meta) {
  const int b = blockIdx.x;
  const int lane = threadIdx.x;
  const int lc = lane < CC ? lane : CC - 1;
  float Trow[CC];  // trans[to=lane][frm=j]
#pragma unroll
  for (int j = 0; j < CC; ++j) Trow[j] = trans[lc * CC + j];
  const float Tstop = trans[STOP_I * CC + lc];

  int n = 0;
#pragma unroll
  for (int k = 0; k < 8; ++k) {
    unsigned long long bl = __ballot(mask[b * LL + k * 64 + lane] > 0.0f);
    n += __popcll(bl);
  }

  const float* eb = emit + (size_t)b * LL * CC;
  float st = (lane == START_I) ? 0.0f : NEGV;

  float ebuf[CS];
#pragma unroll
  for (int q = 0; q < CS; ++q) ebuf[q] = eb[q * CC + lc];

  float* pvb = pv + (size_t)b * NCH * CC;
  const int cfull = n >> 4;
  for (int c = 0; c < cfull; ++c) {
    if (lane < CC) pvb[c * CC + lane] = st;  // state BEFORE chunk c (off-chain)
    float en[CS];
#pragma unroll
    for (int q = 0; q < CS; ++q) en[q] = eb[((c + 1) * CS + q) * CC + lc];
#pragma unroll
    for (int q = 0; q < CS; ++q) VSTEP(ebuf[q]);
#pragma unroll
    for (int q = 0; q < CS; ++q) ebuf[q] = en[q];
  }
  const int rem = n & (CS - 1);
  if (rem) {
    if (lane < CC) pvb[cfull * CC + lane] = st;
#pragma unroll
    for (int q = 0; q < CS; ++q) {
      if (q < rem) VSTEP(ebuf[q]);
    }
  }

  float fin = st + Tstop;
  if (lane < CC) out_score[b * CC + lane] = fin;

  // best tag: uniform readlane sweep (strict > keeps first index on ties)
  float bv = -3.0e38f;
  int bt = 0;
#pragma unroll
  for (int k = 0; k < CC; ++k) {
    float v = rlf(fin, k);
    bool g = v > bv;
    bv = g ? v : bv;
    bt = g ? k : bt;
  }
  if (lane == 0) { meta[b] = n; meta[BB + b] = bt; }
}

// ---------------- parallel replay: backpointers from exact checkpoints ----------------
__global__ __launch_bounds__(64) void k_rep(const float* __restrict__ emit,
                                            const float* __restrict__ trans,
                                            const float* __restrict__ pv,
                                            const int* __restrict__ meta,
                                            unsigned char* __restrict__ bp) {
  const int c = blockIdx.x, b = blockIdx.y;
  const int lane = threadIdx.x;
  const int n = meta[b];
  const int t0 = c * CS;
  if (t0 >= n) return;
  const int lc = lane < CC ? lane : CC - 1;
  float Trow[CC];
#pragma unroll
  for (int j = 0; j < CC; ++j) Trow[j] = trans[lc * CC + j];
  float st = pv[((size_t)b * NCH + c) * CC + lc];
  const float* eb = emit + (size_t)b * LL * CC;
  float ev[CS];
#pragma unroll
  for (int q = 0; q < CS; ++q) ev[q] = eb[(t0 + q) * CC + lc];
  unsigned char* bpb = bp + (size_t)b * LL * CC;
  const int m = (n - t0) < CS ? (n - t0) : CS;
#pragma unroll
  for (int q = 0; q < CS; ++q) {
    if (q < m) {
      float cand[CC];
#pragma unroll
      for (int j = 0; j < CC; ++j) cand[j] = rlf(st, j) + Trow[j];
      float m0 = fmaxf(fmaxf(cand[0], cand[1]), cand[2]);
      float m1 = fmaxf(fmaxf(cand[3], cand[4]), cand[5]);
      float m2 = fmaxf(fmaxf(cand[6], cand[7]), cand[8]);
      float m3 = fmaxf(fmaxf(cand[9], cand[10]), cand[11]);
      float m4 = fmaxf(fmaxf(cand[12], cand[13]), cand[14]);
      float m5 = fmaxf(fmaxf(cand[15], cand[16]), cand[17]);
      float m6 = fmaxf(fmaxf(cand[18], cand[19]), cand[20]);
      float n0 = fmaxf(fmaxf(m0, m1), m2);
      float n1 = fmaxf(fmaxf(m3, m4), m5);
      float n2 = fmaxf(m6, cand[21]);
      float mx = fmaxf(fmaxf(n0, n1), n2);
      // first-index argmax over frm (matches jnp.argmax tie-break)
      unsigned u = 0;
#pragma unroll
      for (int j = 0; j < CC; ++j) u |= (cand[j] == mx) ? (1u << j) : 0u;
      int bpi = __builtin_ctz(u);
      if (lane < CC) bpb[(t0 + q) * CC + lane] = (unsigned char)bpi;
      st = mx + ev[q];
    }
  }
}

// ---------------- backtrace: chunk-composed backpointer maps ----------------
__global__ __launch_bounds__(64) void k_back(const unsigned char* __restrict__ bp,
                                             const int* __restrict__ meta,
                                             float* __restrict__ out_path) {
  __shared__ __align__(16) unsigned char bps[LL * CC];  // 11264 B
  __shared__ unsigned char gs[64 * CC];                 // per-chunk composed maps
  const int b = blockIdx.x, lane = threadIdx.x;
  const int n = meta[b];
  const int bt = meta[BB + b];
  const uint32_t* src = (const uint32_t*)(bp + (size_t)b * LL * CC);
  uint32_t* dst = (uint32_t*)bps;
  for (int i = lane; i < (LL * CC) / 4; i += 64) dst[i] = src[i];
  __syncthreads();
  // lane k composes the 8-step map of chunk k (inactive steps = identity)
  const int k = lane;
  for (int c = 0; c < CC; ++c) {
    int tag = c;
#pragma unroll
    for (int j = 7; j >= 0; --j) {
      int t = 8 * k + j;
      int nv = bps[t * CC + tag];
      tag = (t < n) ? nv : tag;
    }
    gs[k * CC + c] = (unsigned char)tag;
  }
  __syncthreads();
  // 64-step dependent chain over chunk maps (broadcast LDS reads)
  int tag = bt, entry = bt;
  for (int kk = 63; kk >= 0; --kk) {
    if (lane == kk) entry = tag;
    tag = gs[kk * CC + tag];
  }
  // parallel replay within each chunk
  tag = entry;
  float* op = out_path + (size_t)b * LL;
#pragma unroll
  for (int j = 7; j >= 0; --j) {
    int t = 8 * k + j;
    bool act = t < n;
    op[t] = act ? (float)tag : 0.0f;
    int nv = bps[t * CC + tag];
    tag = act ? nv : tag;
  }
}

extern "C" void kernel_launch(void* const* d_in, const int* in_sizes, int n_in,
                              void* d_out, int out_size, void* d_ws, size_t ws_size,
                              hipStream_t stream) {
  const float* x = (const float*)d_in[0];
  const float* mask = (const float*)d_in[1];
  const float* W = (const float*)d_in[2];
  const float* bias = (const float*)d_in[3];
  const float* trans = (const float*)d_in[4];
  float* out_score = (float*)d_out;                 // [B, C] f32
  float* out_path = (float*)d_out + BB * CC;        // [B, L] written as f32 values
  char* ws = (char*)d_ws;
  float* emit = (float*)ws;
  unsigned char* bp = (unsigned char*)(ws + BP_OFF);
  int* meta = (int*)(ws + META_OFF);
  float* pvp = (float*)(ws + PV_OFF);

  k_emit<<<dim3(704), dim3(256), 0, stream>>>(x, W, bias, emit);
  k_pfx<<<dim3(BB), dim3(64), 0, stream>>>(emit, mask, trans, out_score, pvp, meta);
  k_rep<<<dim3(NCH, BB), dim3(64), 0, stream>>>(emit, trans, pvp, meta, bp);
  k_back<<<dim3(BB), dim3(64), 0, stream>>>(bp, meta, out_path);
}

// Round 3
// 142.221 us; speedup vs baseline: 1.3583x; 1.1304x over previous
//
#include <hip/hip_runtime.h>
#include <stdint.h>

#define CC 22
#define START_I 20
#define STOP_I 21
#define BB 64
#define LL 512
#define DD 512
#define NEGV -100000.0f
#define NCH 32
#define CS 16

// ws layout
#define EMIT_FLOATS ((BB * LL + CS) * CC)                // + CS rows slack
#define BP_OFF (((EMIT_FLOATS * 4) + 255) & ~255)
#define BP_BYTES (BB * LL * CC)
#define META_OFF ((BP_OFF + BP_BYTES + 255) & ~255)
#define PV_OFF (META_OFF + 1024)                         // 64*32*22 floats

// ---------------- emissions GEMM: emit[row][c] = x[row]·W[c] + b[c] ----------------
__global__ __launch_bounds__(256) void k_emit(const float* __restrict__ x,
                                              const float* __restrict__ W,
                                              const float* __restrict__ bias,
                                              float* __restrict__ emit) {
  __shared__ float Wl[CC * 516];  // row-major, stride 516 (16B aligned, bank-spread)
  int tid = threadIdx.x;
  for (int g = tid; g < CC * DD; g += 256) {
    int c = g >> 9;
    int d = g & (DD - 1);
    Wl[c * 516 + d] = W[g];
  }
  __syncthreads();
  int gtid = blockIdx.x * 256 + tid;  // 704*256 = 180224 = 22 * 8192 exactly
  int c = gtid % CC;
  int rowbase = gtid / CC;            // [0, 8192)
  float bc = bias[c];
  const float4* xr = (const float4*)(x + (size_t)rowbase * DD);
  const int RS = 8192 * (DD / 4);     // float4 stride between the 4 row groups
  const float* wrow = Wl + c * 516;
  float acc0 = 0.f, acc1 = 0.f, acc2 = 0.f, acc3 = 0.f;
#pragma unroll 4
  for (int i = 0; i < DD / 4; ++i) {
    float4 wv = *(const float4*)(wrow + 4 * i);
    float4 a0 = xr[i];
    float4 a1 = xr[i + RS];
    float4 a2 = xr[i + 2 * RS];
    float4 a3 = xr[i + 3 * RS];
    acc0 += a0.x * wv.x + a0.y * wv.y + a0.z * wv.z + a0.w * wv.w;
    acc1 += a1.x * wv.x + a1.y * wv.y + a1.z * wv.z + a1.w * wv.w;
    acc2 += a2.x * wv.x + a2.y * wv.y + a2.z * wv.z + a2.w * wv.w;
    acc3 += a3.x * wv.x + a3.y * wv.y + a3.z * wv.z + a3.w * wv.w;
  }
  emit[(size_t)(rowbase +     0) * CC + c] = acc0 + bc;
  emit[(size_t)(rowbase +  8192) * CC + c] = acc1 + bc;
  emit[(size_t)(rowbase + 16384) * CC + c] = acc2 + bc;
  emit[(size_t)(rowbase + 24576) * CC + c] = acc3 + bc;
}

__device__ __forceinline__ float rlf(float v, int l) {
  return __int_as_float(__builtin_amdgcn_readlane(__float_as_int(v), l));
}

// One exact Viterbi step. All 22 readlanes grouped (hazards overlap), then a
// sched_barrier pin, then adds + max3-fusable tree. DAG identical to reference.
#define VSTEP(EV)                                                  \
  {                                                                \
    float s0  = rlf(st, 0),  s1  = rlf(st, 1),  s2  = rlf(st, 2);  \
    float s3  = rlf(st, 3),  s4  = rlf(st, 4),  s5  = rlf(st, 5);  \
    float s6  = rlf(st, 6),  s7  = rlf(st, 7),  s8  = rlf(st, 8);  \
    float s9  = rlf(st, 9),  s10 = rlf(st, 10), s11 = rlf(st, 11); \
    float s12 = rlf(st, 12), s13 = rlf(st, 13), s14 = rlf(st, 14); \
    float s15 = rlf(st, 15), s16 = rlf(st, 16), s17 = rlf(st, 17); \
    float s18 = rlf(st, 18), s19 = rlf(st, 19), s20 = rlf(st, 20); \
    float s21 = rlf(st, 21);                                       \
    __builtin_amdgcn_sched_barrier(0);                             \
    float d0  = s0  + Trow[0],  d1  = s1  + Trow[1];               \
    float d2  = s2  + Trow[2],  d3  = s3  + Trow[3];               \
    float d4  = s4  + Trow[4],  d5  = s5  + Trow[5];               \
    float d6  = s6  + Trow[6],  d7  = s7  + Trow[7];               \
    float d8  = s8  + Trow[8],  d9  = s9  + Trow[9];               \
    float d10 = s10 + Trow[10], d11 = s11 + Trow[11];              \
    float d12 = s12 + Trow[12], d13 = s13 + Trow[13];              \
    float d14 = s14 + Trow[14], d15 = s15 + Trow[15];              \
    float d16 = s16 + Trow[16], d17 = s17 + Trow[17];              \
    float d18 = s18 + Trow[18], d19 = s19 + Trow[19];              \
    float d20 = s20 + Trow[20], d21 = s21 + Trow[21];              \
    float m0 = fmaxf(fmaxf(d0, d1), d2);                           \
    float m1 = fmaxf(fmaxf(d3, d4), d5);                           \
    float m2 = fmaxf(fmaxf(d6, d7), d8);                           \
    float m3 = fmaxf(fmaxf(d9, d10), d11);                         \
    float m4 = fmaxf(fmaxf(d12, d13), d14);                        \
    float m5 = fmaxf(fmaxf(d15, d16), d17);                        \
    float m6 = fmaxf(fmaxf(d18, d19), d20);                        \
    float n0 = fmaxf(fmaxf(m0, m1), m2);                           \
    float n1 = fmaxf(fmaxf(m3, m4), m5);                           \
    float n2 = fmaxf(m6, d21);                                     \
    float mx = fmaxf(fmaxf(n0, n1), n2);                           \
    st = mx + (EV);                                                \
  }

// ---------------- prefix pass: exact scores only, checkpoint every CS steps ----------
__global__ __launch_bounds__(64, 1) void k_pfx(const float* __restrict__ emit,
                                               const float* __restrict__ mask,
                                               const float* __restrict__ trans,
                                               float* __restrict__ out_score,
                                               float* __restrict__ pv,
                                               int* __restrict__ meta) {
  __shared__ float els[(LL + CS) * CC];  // whole batch's emissions + slack (46.5 KB)
  const int b = blockIdx.x;
  const int lane = threadIdx.x;
  const int lc = lane < CC ? lane : CC - 1;

  // stage emissions: coalesced float4, 44 iters
  {
    const float4* src = (const float4*)(emit + (size_t)b * LL * CC);
    float4* dst = (float4*)els;
#pragma unroll
    for (int i = 0; i < (LL * CC) / 256; ++i) dst[i * 64 + lane] = src[i * 64 + lane];
  }

  float Trow[CC];  // trans[to=lane][frm=j]
#pragma unroll
  for (int j = 0; j < CC; ++j) Trow[j] = trans[lc * CC + j];
  const float Tstop = trans[STOP_I * CC + lc];

  int n = 0;
#pragma unroll
  for (int k = 0; k < 8; ++k) {
    unsigned long long bl = __ballot(mask[b * LL + k * 64 + lane] > 0.0f);
    n += __popcll(bl);
  }

  __syncthreads();

  float st = (lane == START_I) ? 0.0f : NEGV;

  float ebuf[CS];
#pragma unroll
  for (int q = 0; q < CS; ++q) {
    ebuf[q] = els[q * CC + lc];
    asm volatile("" : "+v"(ebuf[q]));  // force into VGPR now
  }

  float* pvb = pv + (size_t)b * NCH * CC;
  const int cfull = n >> 4;
  for (int c = 0; c < cfull; ++c) {
    if (lane < CC) pvb[c * CC + lane] = st;  // state BEFORE chunk c (off-chain)
    float en[CS];
#pragma unroll
    for (int q = 0; q < CS; ++q) {
      en[q] = els[((c + 1) * CS + q) * CC + lc];
      asm volatile("" : "+v"(en[q]));  // keep prefetch live in VGPRs
    }
    VSTEP(ebuf[0])  VSTEP(ebuf[1])  VSTEP(ebuf[2])  VSTEP(ebuf[3])
    VSTEP(ebuf[4])  VSTEP(ebuf[5])  VSTEP(ebuf[6])  VSTEP(ebuf[7])
    VSTEP(ebuf[8])  VSTEP(ebuf[9])  VSTEP(ebuf[10]) VSTEP(ebuf[11])
    VSTEP(ebuf[12]) VSTEP(ebuf[13]) VSTEP(ebuf[14]) VSTEP(ebuf[15])
#pragma unroll
    for (int q = 0; q < CS; ++q) ebuf[q] = en[q];
  }
  const int rem = n & (CS - 1);
  if (rem) {
    if (lane < CC) pvb[cfull * CC + lane] = st;
#pragma unroll
    for (int q = 0; q < CS; ++q) {
      if (q < rem) VSTEP(ebuf[q]);
    }
  }

  float fin = st + Tstop;
  if (lane < CC) out_score[b * CC + lane] = fin;

  // best tag: uniform readlane sweep (strict > keeps first index on ties)
  float bv = -3.0e38f;
  int bt = 0;
#pragma unroll
  for (int k = 0; k < CC; ++k) {
    float v = rlf(fin, k);
    bool g = v > bv;
    bv = g ? v : bv;
    bt = g ? k : bt;
  }
  if (lane == 0) { meta[b] = n; meta[BB + b] = bt; }
}

// ---------------- parallel replay: backpointers from exact checkpoints ----------------
__global__ __launch_bounds__(64) void k_rep(const float* __restrict__ emit,
                                            const float* __restrict__ trans,
                                            const float* __restrict__ pv,
                                            const int* __restrict__ meta,
                                            unsigned char* __restrict__ bp) {
  const int c = blockIdx.x, b = blockIdx.y;
  const int lane = threadIdx.x;
  const int n = meta[b];
  const int t0 = c * CS;
  if (t0 >= n) return;
  const int lc = lane < CC ? lane : CC - 1;
  float Trow[CC];
#pragma unroll
  for (int j = 0; j < CC; ++j) Trow[j] = trans[lc * CC + j];
  float st = pv[((size_t)b * NCH + c) * CC + lc];
  const float* eb = emit + (size_t)b * LL * CC;
  float ev[CS];
#pragma unroll
  for (int q = 0; q < CS; ++q) {
    ev[q] = eb[(t0 + q) * CC + lc];
    asm volatile("" : "+v"(ev[q]));
  }
  unsigned char* bpb = bp + (size_t)b * LL * CC;
  const int m = (n - t0) < CS ? (n - t0) : CS;
#pragma unroll
  for (int q = 0; q < CS; ++q) {
    if (q < m) {
      float cand[CC];
#pragma unroll
      for (int j = 0; j < CC; ++j) cand[j] = rlf(st, j) + Trow[j];
      float m0 = fmaxf(fmaxf(cand[0], cand[1]), cand[2]);
      float m1 = fmaxf(fmaxf(cand[3], cand[4]), cand[5]);
      float m2 = fmaxf(fmaxf(cand[6], cand[7]), cand[8]);
      float m3 = fmaxf(fmaxf(cand[9], cand[10]), cand[11]);
      float m4 = fmaxf(fmaxf(cand[12], cand[13]), cand[14]);
      float m5 = fmaxf(fmaxf(cand[15], cand[16]), cand[17]);
      float m6 = fmaxf(fmaxf(cand[18], cand[19]), cand[20]);
      float n0 = fmaxf(fmaxf(m0, m1), m2);
      float n1 = fmaxf(fmaxf(m3, m4), m5);
      float n2 = fmaxf(m6, cand[21]);
      float mx = fmaxf(fmaxf(n0, n1), n2);
      // first-index argmax over frm (matches jnp.argmax tie-break)
      unsigned u = 0;
#pragma unroll
      for (int j = 0; j < CC; ++j) u |= (cand[j] == mx) ? (1u << j) : 0u;
      int bpi = __builtin_ctz(u);
      if (lane < CC) bpb[(t0 + q) * CC + lane] = (unsigned char)bpi;
      st = mx + ev[q];
    }
  }
}

// ---------------- backtrace: chunk-composed backpointer maps ----------------
__global__ __launch_bounds__(64) void k_back(const unsigned char* __restrict__ bp,
                                             const int* __restrict__ meta,
                                             float* __restrict__ out_path) {
  __shared__ __align__(16) unsigned char bps[LL * CC];  // 11264 B
  __shared__ unsigned char gs[64 * CC];                 // per-chunk composed maps
  const int b = blockIdx.x, lane = threadIdx.x;
  const int n = meta[b];
  const int bt = meta[BB + b];
  const uint32_t* src = (const uint32_t*)(bp + (size_t)b * LL * CC);
  uint32_t* dst = (uint32_t*)bps;
  for (int i = lane; i < (LL * CC) / 4; i += 64) dst[i] = src[i];
  __syncthreads();
  // lane k composes the 8-step map of chunk k (inactive steps = identity)
  const int k = lane;
  for (int c = 0; c < CC; ++c) {
    int tag = c;
#pragma unroll
    for (int j = 7; j >= 0; --j) {
      int t = 8 * k + j;
      int nv = bps[t * CC + tag];
      tag = (t < n) ? nv : tag;
    }
    gs[k * CC + c] = (unsigned char)tag;
  }
  __syncthreads();
  // 64-step dependent chain over chunk maps (broadcast LDS reads)
  int tag = bt, entry = bt;
  for (int kk = 63; kk >= 0; --kk) {
    if (lane == kk) entry = tag;
    tag = gs[kk * CC + tag];
  }
  // parallel replay within each chunk
  tag = entry;
  float* op = out_path + (size_t)b * LL;
#pragma unroll
  for (int j = 7; j >= 0; --j) {
    int t = 8 * k + j;
    bool act = t < n;
    op[t] = act ? (float)tag : 0.0f;
    int nv = bps[t * CC + tag];
    tag = act ? nv : tag;
  }
}

extern "C" void kernel_launch(void* const* d_in, const int* in_sizes, int n_in,
                              void* d_out, int out_size, void* d_ws, size_t ws_size,
                              hipStream_t stream) {
  const float* x = (const float*)d_in[0];
  const float* mask = (const float*)d_in[1];
  const float* W = (const float*)d_in[2];
  const float* bias = (const float*)d_in[3];
  const float* trans = (const float*)d_in[4];
  float* out_score = (float*)d_out;                 // [B, C] f32
  float* out_path = (float*)d_out + BB * CC;        // [B, L] written as f32 values
  char* ws = (char*)d_ws;
  float* emit = (float*)ws;
  unsigned char* bp = (unsigned char*)(ws + BP_OFF);
  int* meta = (int*)(ws + META_OFF);
  float* pvp = (float*)(ws + PV_OFF);

  k_emit<<<dim3(704), dim3(256), 0, stream>>>(x, W, bias, emit);
  k_pfx<<<dim3(BB), dim3(64), 0, stream>>>(emit, mask, trans, out_score, pvp, meta);
  k_rep<<<dim3(NCH, BB), dim3(64), 0, stream>>>(emit, trans, pvp, meta, bp);
  k_back<<<dim3(BB), dim3(64), 0, stream>>>(bp, meta, out_path);
}

// Round 4
// 136.654 us; speedup vs baseline: 1.4136x; 1.0407x over previous
//
#include <hip/hip_runtime.h>
#include <stdint.h>

#define CC 22
#define START_I 20
#define STOP_I 21
#define BB 64
#define LL 512
#define DD 512
#define NEGV -100000.0f
#define NCH 32
#define CS 16

// ws layout
#define EMIT_FLOATS ((BB * LL + CS) * CC)                // + CS rows slack
#define BP_OFF (((EMIT_FLOATS * 4) + 255) & ~255)
#define BP_BYTES (BB * LL * CC)
#define META_OFF ((BP_OFF + BP_BYTES + 255) & ~255)
#define PV_OFF (META_OFF + 1024)                         // 64*32*22 floats

// ---------------- emissions GEMM: emit[row][c] = x[row]·W[c] + b[c] ----------------
// 2 classes per thread: thread = (row, cpair); 11 threads share one x row.
// Per-output reduction order identical to prior rounds (bit-exact).
__global__ __launch_bounds__(256) void k_emit(const float* __restrict__ x,
                                              const float* __restrict__ W,
                                              const float* __restrict__ bias,
                                              float* __restrict__ emit) {
  __shared__ float Wl[CC * 516];  // row-major, stride 516 (16B aligned, bank-spread)
  int tid = threadIdx.x;
  for (int g = tid; g < CC * DD; g += 256) {
    int c = g >> 9;
    int d = g & (DD - 1);
    Wl[c * 516 + d] = W[g];
  }
  __syncthreads();
  int gtid = blockIdx.x * 256 + tid;  // 1408*256 = 360448 = 11 * 32768 exactly
  int c = gtid % 11;
  int row = gtid / 11;                // [0, 32768)
  float b0 = bias[c];
  float b1 = bias[c + 11];
  const float4* xr = (const float4*)(x + (size_t)row * DD);
  const float* w0 = Wl + c * 516;
  const float* w1 = Wl + (c + 11) * 516;
  float acc0 = 0.f, acc1 = 0.f;
#pragma unroll 4
  for (int i = 0; i < DD / 4; ++i) {
    float4 a = xr[i];
    float4 u = *(const float4*)(w0 + 4 * i);
    float4 v = *(const float4*)(w1 + 4 * i);
    acc0 += a.x * u.x + a.y * u.y + a.z * u.z + a.w * u.w;
    acc1 += a.x * v.x + a.y * v.y + a.z * v.z + a.w * v.w;
  }
  emit[(size_t)row * CC + c] = acc0 + b0;
  emit[(size_t)row * CC + c + 11] = acc1 + b1;
}

__device__ __forceinline__ float rlf(float v, int l) {
  return __int_as_float(__builtin_amdgcn_readlane(__float_as_int(v), l));
}
__device__ __forceinline__ float bperm_f(int addr, float v) {
  return __int_as_float(__builtin_amdgcn_ds_bpermute(addr, __float_as_int(v)));
}

// cross-half max via v_permlane32_swap (VALU-speed lane^32 exchange, gfx950)
__device__ __forceinline__ float xteam_max(float mh) {
#if __has_builtin(__builtin_amdgcn_permlane32_swap)
  typedef unsigned v2u __attribute__((ext_vector_type(2)));
  v2u r = __builtin_amdgcn_permlane32_swap(__float_as_uint(mh), __float_as_uint(mh),
                                           false, false);
  return fmaxf(__uint_as_float(r.x), __uint_as_float(r.y));
#else
  float a = mh, b2 = mh;
  asm volatile("v_permlane32_swap_b32 %0, %1" : "+v"(a), "+v"(b2));
  return fmaxf(a, b2);  // a=[hi|hi], b2=[lo|lo]
#endif
}

// One exact Viterbi step, 2-team layout (h = lane>>5 owns frm 11h..11h+10):
// 11 bpermute gathers + 11 adds + max tree + permlane cross-team max.
// fmax is exactly associative -> bit-identical to the reference reduction.
#define VSTEP2(EV)                                                   \
  {                                                                  \
    float g0 = bperm_f(ab + 0, st), g1 = bperm_f(ab + 4, st);        \
    float g2 = bperm_f(ab + 8, st), g3 = bperm_f(ab + 12, st);       \
    float g4 = bperm_f(ab + 16, st), g5 = bperm_f(ab + 20, st);      \
    float g6 = bperm_f(ab + 24, st), g7 = bperm_f(ab + 28, st);      \
    float g8 = bperm_f(ab + 32, st), g9 = bperm_f(ab + 36, st);      \
    float g10 = bperm_f(ab + 40, st);                                \
    float d0 = g0 + Tw[0], d1 = g1 + Tw[1], d2 = g2 + Tw[2];         \
    float d3 = g3 + Tw[3], d4 = g4 + Tw[4], d5 = g5 + Tw[5];         \
    float d6 = g6 + Tw[6], d7 = g7 + Tw[7], d8 = g8 + Tw[8];         \
    float d9 = g9 + Tw[9], d10 = g10 + Tw[10];                       \
    float m0 = fmaxf(fmaxf(d0, d1), d2);                             \
    float m1 = fmaxf(fmaxf(d3, d4), d5);                             \
    float m2 = fmaxf(fmaxf(d6, d7), d8);                             \
    float m3 = fmaxf(d9, d10);                                       \
    float mh = fmaxf(fmaxf(fmaxf(m0, m1), m2), m3);                  \
    st = xteam_max(mh) + (EV);                                       \
  }

// ---------------- prefix pass: exact scores only, checkpoint every CS steps ----------
__global__ __launch_bounds__(64, 1) void k_pfx(const float* __restrict__ emit,
                                               const float* __restrict__ mask,
                                               const float* __restrict__ trans,
                                               float* __restrict__ out_score,
                                               float* __restrict__ pv,
                                               int* __restrict__ meta) {
  const int b = blockIdx.x;
  const int lane = threadIdx.x;
  const int h = lane >> 5;       // team: which frm half
  const int p = lane & 31;       // to-state (valid < CC)
  const int toc = p < CC ? p : CC - 1;

  float Tw[11];  // trans[to=p][frm=11h+j]
#pragma unroll
  for (int j = 0; j < 11; ++j) Tw[j] = trans[toc * CC + 11 * h + j];
  const float Tstop = trans[STOP_I * CC + toc];
  const int ab = 44 * h;  // bpermute byte base: gathers st from lanes 11h+j

  int n = 0;
#pragma unroll
  for (int k = 0; k < 8; ++k) {
    unsigned long long bl = __ballot(mask[b * LL + k * 64 + lane] > 0.0f);
    n += __popcll(bl);
  }

  const float* eb = emit + (size_t)b * LL * CC;
  float st = (p == START_I) ? 0.0f : NEGV;

  float ebuf[CS];
#pragma unroll
  for (int q = 0; q < CS; ++q) {
    ebuf[q] = eb[q * CC + toc];
    asm volatile("" : "+v"(ebuf[q]));  // cold-start materialize (once)
  }

  float* pvb = pv + (size_t)b * NCH * CC;
  const int cfull = n >> 4;
  for (int c = 0; c < cfull; ++c) {
    if (lane < CC) pvb[c * CC + lane] = st;  // state BEFORE chunk c (off-chain)
    float en[CS];
#pragma unroll
    for (int q = 0; q < CS; ++q) en[q] = eb[((c + 1) * CS + q) * CC + toc];  // issue early
    VSTEP2(ebuf[0])  VSTEP2(ebuf[1])  VSTEP2(ebuf[2])  VSTEP2(ebuf[3])
    VSTEP2(ebuf[4])  VSTEP2(ebuf[5])  VSTEP2(ebuf[6])  VSTEP2(ebuf[7])
    VSTEP2(ebuf[8])  VSTEP2(ebuf[9])  VSTEP2(ebuf[10]) VSTEP2(ebuf[11])
    VSTEP2(ebuf[12]) VSTEP2(ebuf[13]) VSTEP2(ebuf[14]) VSTEP2(ebuf[15])
#pragma unroll
    for (int q = 0; q < CS; ++q) {
      asm volatile("" : "+v"(en[q]));  // vmcnt wait lands HERE (after compute)
      ebuf[q] = en[q];
    }
  }
  const int rem = n & (CS - 1);
  if (rem) {
    if (lane < CC) pvb[cfull * CC + lane] = st;
#pragma unroll
    for (int q = 0; q < CS; ++q) {
      if (q < rem) VSTEP2(ebuf[q]);  // uniform branch, exec stays full
    }
  }

  float fin = st + Tstop;
  if (lane < CC) out_score[b * CC + lane] = fin;

  // best tag: uniform readlane sweep (strict > keeps first index on ties)
  float bv = -3.0e38f;
  int bt = 0;
#pragma unroll
  for (int k = 0; k < CC; ++k) {
    float v = rlf(fin, k);
    bool g = v > bv;
    bv = g ? v : bv;
    bt = g ? k : bt;
  }
  if (lane == 0) { meta[b] = n; meta[BB + b] = bt; }
}

// ---------------- parallel replay: backpointers from exact checkpoints ----------------
__global__ __launch_bounds__(64) void k_rep(const float* __restrict__ emit,
                                            const float* __restrict__ trans,
                                            const float* __restrict__ pv,
                                            const int* __restrict__ meta,
                                            unsigned char* __restrict__ bp) {
  const int c = blockIdx.x, b = blockIdx.y;
  const int lane = threadIdx.x;
  const int n = meta[b];
  const int t0 = c * CS;
  if (t0 >= n) return;
  const int lc = lane < CC ? lane : CC - 1;
  float Trow[CC];
#pragma unroll
  for (int j = 0; j < CC; ++j) Trow[j] = trans[lc * CC + j];
  float st = pv[((size_t)b * NCH + c) * CC + lc];
  const float* eb = emit + (size_t)b * LL * CC;
  float ev[CS];
#pragma unroll
  for (int q = 0; q < CS; ++q) {
    ev[q] = eb[(t0 + q) * CC + lc];
    asm volatile("" : "+v"(ev[q]));
  }
  unsigned char* bpb = bp + (size_t)b * LL * CC;
  const int m = (n - t0) < CS ? (n - t0) : CS;
#pragma unroll
  for (int q = 0; q < CS; ++q) {
    if (q < m) {
      float cand[CC];
#pragma unroll
      for (int j = 0; j < CC; ++j) cand[j] = rlf(st, j) + Trow[j];
      float m0 = fmaxf(fmaxf(cand[0], cand[1]), cand[2]);
      float m1 = fmaxf(fmaxf(cand[3], cand[4]), cand[5]);
      float m2 = fmaxf(fmaxf(cand[6], cand[7]), cand[8]);
      float m3 = fmaxf(fmaxf(cand[9], cand[10]), cand[11]);
      float m4 = fmaxf(fmaxf(cand[12], cand[13]), cand[14]);
      float m5 = fmaxf(fmaxf(cand[15], cand[16]), cand[17]);
      float m6 = fmaxf(fmaxf(cand[18], cand[19]), cand[20]);
      float n0 = fmaxf(fmaxf(m0, m1), m2);
      float n1 = fmaxf(fmaxf(m3, m4), m5);
      float n2 = fmaxf(m6, cand[21]);
      float mx = fmaxf(fmaxf(n0, n1), n2);
      // first-index argmax over frm (matches jnp.argmax tie-break)
      unsigned u = 0;
#pragma unroll
      for (int j = 0; j < CC; ++j) u |= (cand[j] == mx) ? (1u << j) : 0u;
      int bpi = __builtin_ctz(u);
      if (lane < CC) bpb[(t0 + q) * CC + lane] = (unsigned char)bpi;
      st = mx + ev[q];
    }
  }
}

// ---------------- backtrace: chunk-composed backpointer maps ----------------
__global__ __launch_bounds__(64) void k_back(const unsigned char* __restrict__ bp,
                                             const int* __restrict__ meta,
                                             float* __restrict__ out_path) {
  __shared__ __align__(16) unsigned char bps[LL * CC];  // 11264 B
  __shared__ unsigned char gs[64 * CC];                 // per-chunk composed maps
  const int b = blockIdx.x, lane = threadIdx.x;
  const int n = meta[b];
  const int bt = meta[BB + b];
  const uint32_t* src = (const uint32_t*)(bp + (size_t)b * LL * CC);
  uint32_t* dst = (uint32_t*)bps;
  for (int i = lane; i < (LL * CC) / 4; i += 64) dst[i] = src[i];
  __syncthreads();
  // lane k composes the 8-step map of chunk k (inactive steps = identity)
  const int k = lane;
  for (int c = 0; c < CC; ++c) {
    int tag = c;
#pragma unroll
    for (int j = 7; j >= 0; --j) {
      int t = 8 * k + j;
      int nv = bps[t * CC + tag];
      tag = (t < n) ? nv : tag;
    }
    gs[k * CC + c] = (unsigned char)tag;
  }
  __syncthreads();
  // 64-step dependent chain over chunk maps (broadcast LDS reads)
  int tag = bt, entry = bt;
  for (int kk = 63; kk >= 0; --kk) {
    if (lane == kk) entry = tag;
    tag = gs[kk * CC + tag];
  }
  // parallel replay within each chunk
  tag = entry;
  float* op = out_path + (size_t)b * LL;
#pragma unroll
  for (int j = 7; j >= 0; --j) {
    int t = 8 * k + j;
    bool act = t < n;
    op[t] = act ? (float)tag : 0.0f;
    int nv = bps[t * CC + tag];
    tag = act ? nv : tag;
  }
}

extern "C" void kernel_launch(void* const* d_in, const int* in_sizes, int n_in,
                              void* d_out, int out_size, void* d_ws, size_t ws_size,
                              hipStream_t stream) {
  const float* x = (const float*)d_in[0];
  const float* mask = (const float*)d_in[1];
  const float* W = (const float*)d_in[2];
  const float* bias = (const float*)d_in[3];
  const float* trans = (const float*)d_in[4];
  float* out_score = (float*)d_out;                 // [B, C] f32
  float* out_path = (float*)d_out + BB * CC;        // [B, L] written as f32 values
  char* ws = (char*)d_ws;
  float* emit = (float*)ws;
  unsigned char* bp = (unsigned char*)(ws + BP_OFF);
  int* meta = (int*)(ws + META_OFF);
  float* pvp = (float*)(ws + PV_OFF);

  k_emit<<<dim3(1408), dim3(256), 0, stream>>>(x, W, bias, emit);
  k_pfx<<<dim3(BB), dim3(64), 0, stream>>>(emit, mask, trans, out_score, pvp, meta);
  k_rep<<<dim3(NCH, BB), dim3(64), 0, stream>>>(emit, trans, pvp, meta, bp);
  k_back<<<dim3(BB), dim3(64), 0, stream>>>(bp, meta, out_path);
}